// Round 5
// baseline (84.646 us; speedup 1.0000x reference)
//
#include <hip/hip_runtime.h>
#include <math.h>

#define BATCH 32
#define NPTS 1024
#define DIM 64
#define EPS_DIV 1e-8f
#define EPS_NORM 1e-8f

typedef __attribute__((ext_vector_type(8))) short short8v;
typedef __attribute__((ext_vector_type(4))) float f32x4;

static __device__ __forceinline__ unsigned short f2bf(float f) {
    unsigned u = __float_as_uint(f);
    return (unsigned short)((u + 0x7FFFu + ((u >> 16) & 1u)) >> 16);
}
static __device__ __forceinline__ float bf2f(unsigned short h) {
    return __uint_as_float(((unsigned)h) << 16);
}
static __device__ __forceinline__ float fsqrt(float x) {
#if __has_builtin(__builtin_amdgcn_sqrtf)
    return __builtin_amdgcn_sqrtf(x);
#else
    return sqrtf(x);
#endif
}

// ---- pass 1: coalesced total-sum partials + bf16 cast + per-row sumsq ----
__global__ __launch_bounds__(256) void k_prep(const float* __restrict__ p,
                                              const float* __restrict__ q,
                                              unsigned short* __restrict__ xb,
                                              float* __restrict__ rr,
                                              float* __restrict__ scpart) {
    int b = blockIdx.z, sel = blockIdx.y, chunk = blockIdx.x;   // 256-row chunk
    const float* src = (sel ? q : p) + ((size_t)b * NPTS + chunk * 256) * DIM;
    unsigned short* dst = xb + (size_t)sel * (BATCH * NPTS * DIM)
                             + ((size_t)b * NPTS + chunk * 256) * DIM;
    float* rrb = rr + (size_t)sel * (BATCH * NPTS) + b * NPTS + chunk * 256;
    int t = threadIdx.x;
    float s = 0.f;
    #pragma unroll
    for (int it = 0; it < 16; it++) {
        int idx = it * 256 + t;              // float4 unit; 16 per row
        float4 v = ((const float4*)src)[idx];
        s += v.x + v.y + v.z + v.w;
        unsigned short h0 = f2bf(v.x), h1 = f2bf(v.y), h2 = f2bf(v.z), h3 = f2bf(v.w);
        float r0 = bf2f(h0), r1 = bf2f(h1), r2 = bf2f(h2), r3 = bf2f(h3);
        float ss = r0 * r0 + r1 * r1 + r2 * r2 + r3 * r3;
        ushort4 o; o.x = h0; o.y = h1; o.z = h2; o.w = h3;
        ((ushort4*)dst)[idx] = o;
        // row sumsq: 16 consecutive lanes hold one row
        ss += __shfl_xor(ss, 1);
        ss += __shfl_xor(ss, 2);
        ss += __shfl_xor(ss, 4);
        ss += __shfl_xor(ss, 8);
        if ((t & 15) == 0) rrb[it * 16 + (t >> 4)] = ss;
    }
    __shared__ float sm[256];
    sm[t] = s;
    __syncthreads();
    for (int st = 128; st > 0; st >>= 1) {
        if (t < st) sm[t] += sm[t + st];
        __syncthreads();
    }
    if (t == 0) scpart[(sel * BATCH + b) * 4 + chunk] = sm[0];
}

// ---- pass A: column sums of r = sqrt(sqd) (m = 10*r folded later) ----
__global__ __launch_bounds__(256) void k_colsum(const unsigned short* __restrict__ xb,
                                                const float* __restrict__ rr,
                                                const float* __restrict__ scpart,
                                                float* __restrict__ cspart) {
    int b = blockIdx.z, tI = blockIdx.y, tJ = blockIdx.x;
    int i0 = tI * 128, j0 = tJ * 128;
    __shared__ float cs[2][128];
    int t = threadIdx.x;
    int lane = t & 63, w = t >> 6;
    int wr = w >> 1, wc = w & 1;
    int lr = lane & 15, lk = lane >> 4;
    float sps = 0.f, sqs = 0.f;
    #pragma unroll
    for (int c = 0; c < 4; c++) {
        sps += scpart[b * 4 + c];
        sqs += scpart[(BATCH + b) * 4 + c];
    }
    float sp = 1.0f / (sps + EPS_NORM), sq = 1.0f / (sqs + EPS_NORM);
    float sp2 = sp * sp, sq2 = sq * sq, spq2 = 2.f * sp * sq;
    const unsigned short* xbase = xb + ((size_t)b * NPTS + i0 + wr * 64) * DIM;
    const unsigned short* ybase = xb + (size_t)(BATCH * NPTS * DIM)
                                     + ((size_t)b * NPTS + j0 + wc * 64) * DIM;
    f32x4 acc[4][4];
    #pragma unroll
    for (int m = 0; m < 4; m++)
        #pragma unroll
        for (int n = 0; n < 4; n++) acc[m][n] = (f32x4){0.f, 0.f, 0.f, 0.f};
    #pragma unroll
    for (int ks = 0; ks < 2; ks++) {
        int co = ks * 32 + lk * 8;
        short8v am[4], bn[4];
        #pragma unroll
        for (int m = 0; m < 4; m++)
            am[m] = *(const short8v*)(xbase + (size_t)(m * 16 + lr) * DIM + co);
        #pragma unroll
        for (int n = 0; n < 4; n++)
            bn[n] = *(const short8v*)(ybase + (size_t)(n * 16 + lr) * DIM + co);
        #pragma unroll
        for (int m = 0; m < 4; m++)
            #pragma unroll
            for (int n = 0; n < 4; n++)
                acc[m][n] = __builtin_amdgcn_mfma_f32_16x16x32_bf16(
                    am[m], bn[n], acc[m][n], 0, 0, 0);
    }
    const float* rrp = rr + b * NPTS + i0 + wr * 64;
    const float* rrq = rr + (size_t)BATCH * NPTS + b * NPTS + j0 + wc * 64;
    float csn[4] = {0.f, 0.f, 0.f, 0.f};
    #pragma unroll
    for (int m = 0; m < 4; m++) {
        float xr[4];
        #pragma unroll
        for (int r = 0; r < 4; r++)
            xr[r] = sp2 * rrp[m * 16 + lk * 4 + r];
        #pragma unroll
        for (int n = 0; n < 4; n++) {
            float yr = sq2 * rrq[n * 16 + lr];
            #pragma unroll
            for (int r = 0; r < 4; r++) {
                float sqd = fmaxf(xr[r] + yr - spq2 * acc[m][n][r], 0.f);
                csn[n] += fsqrt(sqd);
            }
        }
    }
    #pragma unroll
    for (int n = 0; n < 4; n++) {
        float vv = csn[n];
        vv += __shfl_xor(vv, 16);
        vv += __shfl_xor(vv, 32);
        if (lk == 0) cs[wr][wc * 64 + n * 16 + lr] = vv;
    }
    __syncthreads();
    if (t < 128)
        cspart[((size_t)tI * BATCH + b) * NPTS + j0 + t] = cs[0][t] + cs[1][t];
}

// ---- v_j = 1/(1 - 10*colsum_j/N + eps); per-chunk v sums ----
__global__ __launch_bounds__(256) void k_vinit(const float* __restrict__ cspart,
                                               float* __restrict__ v,
                                               float* __restrict__ svpart) {
    int b = blockIdx.y;
    int j = blockIdx.x * 256 + threadIdx.x;
    float s = 0.f;
    #pragma unroll
    for (int ti = 0; ti < 8; ti++) s += cspart[((size_t)ti * BATCH + b) * NPTS + j];
    float vj = 1.0f / (1.0f - s * (10.0f / NPTS) + EPS_DIV);
    v[b * NPTS + j] = vj;
    __shared__ float sm[256];
    sm[threadIdx.x] = vj;
    __syncthreads();
    for (int st = 128; st > 0; st >>= 1) {
        if (threadIdx.x < st) sm[threadIdx.x] += sm[threadIdx.x + st];
        __syncthreads();
    }
    if (threadIdx.x == 0) svpart[b * 4 + blockIdx.x] = sm[0];
}

// ---- pass B: 64 rows x 256 cols per block -> a1,a2 row partials ----
// a1' = sum_j r*v  (rowdot = 10*a1'), a2 = sum_j v*r*(1-10r) (exact loss term)
__global__ __launch_bounds__(256) void k_loss(const unsigned short* __restrict__ xb,
                                              const float* __restrict__ rr,
                                              const float* __restrict__ scpart,
                                              const float* __restrict__ v,
                                              float* __restrict__ a1part,
                                              float* __restrict__ a2part) {
    int cc = blockIdx.x, tI = blockIdx.y, b = blockIdx.z;
    int i0 = tI * 64, j0 = cc * 256;
    int t = threadIdx.x;
    int lane = t & 63, w = t >> 6;
    int lr = lane & 15, lk = lane >> 4;
    float sps = 0.f, sqs = 0.f;
    #pragma unroll
    for (int c = 0; c < 4; c++) {
        sps += scpart[b * 4 + c];
        sqs += scpart[(BATCH + b) * 4 + c];
    }
    float sp = 1.0f / (sps + EPS_NORM), sq = 1.0f / (sqs + EPS_NORM);
    float sp2 = sp * sp, sq2 = sq * sq, spq2 = 2.f * sp * sq;
    const unsigned short* xrow = xb + ((size_t)b * NPTS + i0 + w * 16 + lr) * DIM;
    short8v am0 = *(const short8v*)(xrow + lk * 8);
    short8v am1 = *(const short8v*)(xrow + 32 + lk * 8);
    float xr[4];
    #pragma unroll
    for (int r = 0; r < 4; r++)
        xr[r] = sp2 * rr[b * NPTS + i0 + w * 16 + lk * 4 + r];
    const unsigned short* ybase = xb + (size_t)(BATCH * NPTS * DIM)
                                     + (size_t)b * NPTS * DIM;
    const float* rrq = rr + (size_t)BATCH * NPTS + b * NPTS;
    const float* vb = v + b * NPTS;
    float a1[4] = {0.f, 0.f, 0.f, 0.f}, a2[4] = {0.f, 0.f, 0.f, 0.f};
    #pragma unroll 2
    for (int nt = 0; nt < 16; nt++) {
        int col = j0 + nt * 16 + lr;
        const unsigned short* yrow = ybase + (size_t)col * DIM;
        short8v bn0 = *(const short8v*)(yrow + lk * 8);
        short8v bn1 = *(const short8v*)(yrow + 32 + lk * 8);
        f32x4 acc = (f32x4){0.f, 0.f, 0.f, 0.f};
        acc = __builtin_amdgcn_mfma_f32_16x16x32_bf16(am0, bn0, acc, 0, 0, 0);
        acc = __builtin_amdgcn_mfma_f32_16x16x32_bf16(am1, bn1, acc, 0, 0, 0);
        float yr = sq2 * rrq[col];
        float vj = vb[col];
        #pragma unroll
        for (int r = 0; r < 4; r++) {
            float sqd = fmaxf(xr[r] + yr - spq2 * acc[r], 0.f);
            float rt = fsqrt(sqd);
            float tv = rt * vj;
            a1[r] += tv;
            a2[r] += tv * (1.0f - 10.0f * rt);
        }
    }
    #pragma unroll
    for (int r = 0; r < 4; r++) {
        #pragma unroll
        for (int s = 1; s < 16; s <<= 1) {
            a1[r] += __shfl_xor(a1[r], s);
            a2[r] += __shfl_xor(a2[r], s);
        }
    }
    if (lr == 0) {
        #pragma unroll
        for (int r = 0; r < 4; r++) {
            int row = i0 + w * 16 + lk * 4 + r;
            a1part[((size_t)b * NPTS + row) * 4 + cc] = a1[r];
            a2part[((size_t)b * NPTS + row) * 4 + cc] = a2[r];
        }
    }
}

// ---- per-batch: u_i = 1/(sV - 10*a1_i + eps); loss_b = sum u_i*a2_i ----
__global__ __launch_bounds__(256) void k_rowfinal(const float* __restrict__ a1part,
                                                  const float* __restrict__ a2part,
                                                  const float* __restrict__ svpart,
                                                  float* __restrict__ lossb) {
    int b = blockIdx.x;
    int t = threadIdx.x;
    float sV = svpart[b * 4] + svpart[b * 4 + 1] + svpart[b * 4 + 2] + svpart[b * 4 + 3];
    float lp = 0.f;
    #pragma unroll
    for (int rr4 = 0; rr4 < 4; rr4++) {
        int row = rr4 * 256 + t;
        const float* p1 = a1part + ((size_t)b * NPTS + row) * 4;
        const float* p2 = a2part + ((size_t)b * NPTS + row) * 4;
        float a1 = p1[0] + p1[1] + p1[2] + p1[3];
        float a2 = p2[0] + p2[1] + p2[2] + p2[3];
        float u = 1.0f / (sV - 10.0f * a1 + EPS_DIV);
        lp += u * a2;
    }
    __shared__ float sm[256];
    sm[t] = lp;
    __syncthreads();
    for (int st = 128; st > 0; st >>= 1) {
        if (t < st) sm[t] += sm[t + st];
        __syncthreads();
    }
    if (t == 0) lossb[b] = sm[0];
}

__global__ void k_out(const float* __restrict__ lossb, float* __restrict__ out) {
    if (threadIdx.x == 0) {
        float s = 0.f;
        #pragma unroll
        for (int b = 0; b < BATCH; b++) s += lossb[b];
        out[0] = s / (float)BATCH;
    }
}

extern "C" void kernel_launch(void* const* d_in, const int* in_sizes, int n_in,
                              void* d_out, int out_size, void* d_ws, size_t ws_size,
                              hipStream_t stream) {
    const float* pred   = (const float*)d_in[0];
    const float* target = (const float*)d_in[1];
    float* out = (float*)d_out;

    unsigned short* xb = (unsigned short*)d_ws;                   // 8 MB bf16
    float* fs = (float*)(xb + (size_t)2 * BATCH * NPTS * DIM);
    float* rr     = fs;                                           // 65536
    float* cspart = rr + 2 * BATCH * NPTS;                        // 262144
    float* v      = cspart + 8 * BATCH * NPTS;                    // 32768
    float* scpart = v + BATCH * NPTS;                             // 256
    float* svpart = scpart + 256;                                 // 128
    float* a1part = svpart + 128;                                 // 131072
    float* a2part = a1part + 4 * BATCH * NPTS;                    // 131072
    float* lossb  = a2part + 4 * BATCH * NPTS;                    // 32

    k_prep<<<dim3(4, 2, BATCH), 256, 0, stream>>>(pred, target, xb, rr, scpart);
    k_colsum<<<dim3(8, 8, BATCH), 256, 0, stream>>>(xb, rr, scpart, cspart);
    k_vinit<<<dim3(4, BATCH), 256, 0, stream>>>(cspart, v, svpart);
    k_loss<<<dim3(4, 16, BATCH), 256, 0, stream>>>(xb, rr, scpart, v, a1part, a2part);
    k_rowfinal<<<BATCH, 256, 0, stream>>>(a1part, a2part, svpart, lossb);
    k_out<<<1, 64, 0, stream>>>(lossb, out);
}

// Round 6
// 56.342 us; speedup vs baseline: 1.5024x; 1.5024x over previous
//
#include <hip/hip_runtime.h>
#include <math.h>

#define BATCH 32
#define NPTS 1024
#define DIM 64
#define EPS_DIV 1e-8f
#define EPS_NORM 1e-8f
#define BN (BATCH * NPTS)
#define OFFQ ((size_t)BATCH * NPTS * DIM)

typedef __attribute__((ext_vector_type(8))) short short8v;
typedef __attribute__((ext_vector_type(4))) float f32x4;

static __device__ __forceinline__ unsigned short f2bf(float f) {
    unsigned u = __float_as_uint(f);
    return (unsigned short)((u + 0x7FFFu + ((u >> 16) & 1u)) >> 16);
}
static __device__ __forceinline__ float bf2f(unsigned short h) {
    return __uint_as_float(((unsigned)h) << 16);
}
static __device__ __forceinline__ float fsqrt(float x) {
#if __has_builtin(__builtin_amdgcn_sqrtf)
    return __builtin_amdgcn_sqrtf(x);
#else
    return sqrtf(x);
#endif
}

// ---- prep: 64-row chunks, fully coalesced; grid (16,2,BATCH) x 256 ----
__global__ __launch_bounds__(256) void k_prep(const float* __restrict__ p,
                                              const float* __restrict__ q,
                                              unsigned short* __restrict__ xb,
                                              float* __restrict__ rr,
                                              float* __restrict__ scpart) {
    int b = blockIdx.z, sel = blockIdx.y, chunk = blockIdx.x;
    const float* src = (sel ? q : p) + ((size_t)b * NPTS + chunk * 64) * DIM;
    unsigned short* dst = xb + (sel ? OFFQ : 0)
                             + ((size_t)b * NPTS + chunk * 64) * DIM;
    float* rrb = rr + sel * BN + b * NPTS + chunk * 64;
    int t = threadIdx.x;
    float s = 0.f;
    #pragma unroll
    for (int it = 0; it < 4; it++) {
        int idx = it * 256 + t;              // float4 unit; 16 per row
        float4 v = ((const float4*)src)[idx];
        s += v.x + v.y + v.z + v.w;
        unsigned short h0 = f2bf(v.x), h1 = f2bf(v.y), h2 = f2bf(v.z), h3 = f2bf(v.w);
        float r0 = bf2f(h0), r1 = bf2f(h1), r2 = bf2f(h2), r3 = bf2f(h3);
        float ss = r0 * r0 + r1 * r1 + r2 * r2 + r3 * r3;
        ushort4 o; o.x = h0; o.y = h1; o.z = h2; o.w = h3;
        ((ushort4*)dst)[idx] = o;
        ss += __shfl_xor(ss, 1);
        ss += __shfl_xor(ss, 2);
        ss += __shfl_xor(ss, 4);
        ss += __shfl_xor(ss, 8);
        if ((t & 15) == 0) rrb[it * 16 + (t >> 4)] = ss;
    }
    __shared__ float sm[256];
    sm[t] = s;
    __syncthreads();
    for (int st = 128; st > 0; st >>= 1) {
        if (t < st) sm[t] += sm[t + st];
        __syncthreads();
    }
    if (t == 0) scpart[(sel * BATCH + b) * 16 + chunk] = sm[0];
}

// ---- pass A: block owns 64 cols x ALL rows -> v directly; grid (16,BATCH) x 512 ----
__global__ __launch_bounds__(512) void k_colsum(const unsigned short* __restrict__ xb,
                                                const float* __restrict__ rr,
                                                const float* __restrict__ scpart,
                                                float* __restrict__ v,
                                                float* __restrict__ svpart) {
    int b = blockIdx.y, j0 = blockIdx.x * 64;
    int t = threadIdx.x, lane = t & 63, w = t >> 6;
    int lr = lane & 15, lk = lane >> 4;
    float sps = 0.f, sqs = 0.f;
    #pragma unroll
    for (int c = 0; c < 16; c++) {
        sps += scpart[b * 16 + c];
        sqs += scpart[(BATCH + b) * 16 + c];
    }
    float sp = 1.0f / (sps + EPS_NORM), sq = 1.0f / (sqs + EPS_NORM);
    float sp2 = sp * sp, sq2 = sq * sq, spq2 = 2.f * sp * sq;
    const unsigned short* ybase = xb + OFFQ + ((size_t)b * NPTS + j0) * DIM;
    const unsigned short* xbase = xb + (size_t)b * NPTS * DIM;
    const float* rrp = rr + b * NPTS;
    const float* rrq = rr + BN + b * NPTS;
    // hoisted B fragments + yr (fixed for the whole block)
    short8v bn[2][4];
    #pragma unroll
    for (int ks = 0; ks < 2; ks++)
        #pragma unroll
        for (int n = 0; n < 4; n++)
            bn[ks][n] = *(const short8v*)(ybase + (size_t)(n * 16 + lr) * DIM
                                          + ks * 32 + lk * 8);
    float yr[4];
    #pragma unroll
    for (int n = 0; n < 4; n++) yr[n] = sq2 * rrq[j0 + n * 16 + lr];
    float csn[4] = {0.f, 0.f, 0.f, 0.f};
    #pragma unroll
    for (int it = 0; it < 2; it++) {
        int ib = w * 128 + it * 64;
        f32x4 acc[4][4];
        #pragma unroll
        for (int m = 0; m < 4; m++)
            #pragma unroll
            for (int n = 0; n < 4; n++) acc[m][n] = (f32x4){0.f, 0.f, 0.f, 0.f};
        #pragma unroll
        for (int ks = 0; ks < 2; ks++) {
            short8v am[4];
            #pragma unroll
            for (int m = 0; m < 4; m++)
                am[m] = *(const short8v*)(xbase + (size_t)(ib + m * 16 + lr) * DIM
                                          + ks * 32 + lk * 8);
            #pragma unroll
            for (int m = 0; m < 4; m++)
                #pragma unroll
                for (int n = 0; n < 4; n++)
                    acc[m][n] = __builtin_amdgcn_mfma_f32_16x16x32_bf16(
                        am[m], bn[ks][n], acc[m][n], 0, 0, 0);
        }
        #pragma unroll
        for (int m = 0; m < 4; m++) {
            float4 xr = *(const float4*)(rrp + ib + m * 16 + lk * 4);
            xr.x *= sp2; xr.y *= sp2; xr.z *= sp2; xr.w *= sp2;
            float xs[4] = {xr.x, xr.y, xr.z, xr.w};
            #pragma unroll
            for (int n = 0; n < 4; n++)
                #pragma unroll
                for (int r = 0; r < 4; r++) {
                    float sqd = fmaxf(xs[r] + yr[n] - spq2 * acc[m][n][r], 0.f);
                    csn[n] += fsqrt(sqd);
                }
        }
    }
    #pragma unroll
    for (int n = 0; n < 4; n++) {
        csn[n] += __shfl_xor(csn[n], 16);
        csn[n] += __shfl_xor(csn[n], 32);
    }
    __shared__ float cs[8][64];
    if (lk == 0) {
        #pragma unroll
        for (int n = 0; n < 4; n++) cs[w][n * 16 + lr] = csn[n];
    }
    __syncthreads();
    if (t < 64) {
        float s = 0.f;
        #pragma unroll
        for (int ww = 0; ww < 8; ww++) s += cs[ww][t];
        float vj = 1.0f / (1.0f - s * (10.0f / NPTS) + EPS_DIV);
        v[b * NPTS + j0 + t] = vj;
        float sv = vj;
        #pragma unroll
        for (int st = 1; st < 64; st <<= 1) sv += __shfl_xor(sv, st);
        if (t == 0) svpart[b * 16 + blockIdx.x] = sv;
    }
}

// ---- pass B: block owns 64 rows x ALL cols -> u + loss partial; grid (16,BATCH) x 512 ----
__global__ __launch_bounds__(512) void k_loss(const unsigned short* __restrict__ xb,
                                              const float* __restrict__ rr,
                                              const float* __restrict__ scpart,
                                              const float* __restrict__ v,
                                              const float* __restrict__ svpart,
                                              float* __restrict__ parts) {
    int b = blockIdx.y, i0 = blockIdx.x * 64;
    int t = threadIdx.x, lane = t & 63, w = t >> 6;
    int lr = lane & 15, lk = lane >> 4;
    __shared__ float sv[NPTS];
    __shared__ float a1s[8][64], a2s[8][64];
    if (t < 256) ((float4*)sv)[t] = ((const float4*)(v + (size_t)b * NPTS))[t];
    float sV = 0.f;
    #pragma unroll
    for (int k = 0; k < 16; k++) sV += svpart[b * 16 + k];
    float sps = 0.f, sqs = 0.f;
    #pragma unroll
    for (int c = 0; c < 16; c++) {
        sps += scpart[b * 16 + c];
        sqs += scpart[(BATCH + b) * 16 + c];
    }
    float sp = 1.0f / (sps + EPS_NORM), sq = 1.0f / (sqs + EPS_NORM);
    float sp2 = sp * sp, sq2 = sq * sq, spq2 = 2.f * sp * sq;
    const unsigned short* xbase = xb + ((size_t)b * NPTS + i0) * DIM;
    const unsigned short* ybase = xb + OFFQ + (size_t)b * NPTS * DIM;
    const float* rrq = rr + BN + b * NPTS;
    // hoisted A fragments + xr (fixed rows for the whole block)
    short8v am[2][4];
    #pragma unroll
    for (int ks = 0; ks < 2; ks++)
        #pragma unroll
        for (int m = 0; m < 4; m++)
            am[ks][m] = *(const short8v*)(xbase + (size_t)(m * 16 + lr) * DIM
                                          + ks * 32 + lk * 8);
    float xs[4][4];
    #pragma unroll
    for (int m = 0; m < 4; m++) {
        float4 xr = *(const float4*)(rr + b * NPTS + i0 + m * 16 + lk * 4);
        xs[m][0] = xr.x * sp2; xs[m][1] = xr.y * sp2;
        xs[m][2] = xr.z * sp2; xs[m][3] = xr.w * sp2;
    }
    float a1[4][4] = {}, a2[4][4] = {};
    __syncthreads();
    #pragma unroll
    for (int it = 0; it < 2; it++) {
        int jb = w * 128 + it * 64;
        f32x4 acc[4][4];
        #pragma unroll
        for (int m = 0; m < 4; m++)
            #pragma unroll
            for (int n = 0; n < 4; n++) acc[m][n] = (f32x4){0.f, 0.f, 0.f, 0.f};
        #pragma unroll
        for (int ks = 0; ks < 2; ks++) {
            short8v bnf[4];
            #pragma unroll
            for (int n = 0; n < 4; n++)
                bnf[n] = *(const short8v*)(ybase + (size_t)(jb + n * 16 + lr) * DIM
                                           + ks * 32 + lk * 8);
            #pragma unroll
            for (int m = 0; m < 4; m++)
                #pragma unroll
                for (int n = 0; n < 4; n++)
                    acc[m][n] = __builtin_amdgcn_mfma_f32_16x16x32_bf16(
                        am[ks][m], bnf[n], acc[m][n], 0, 0, 0);
        }
        float yr[4], vjn[4];
        #pragma unroll
        for (int n = 0; n < 4; n++) {
            yr[n] = sq2 * rrq[jb + n * 16 + lr];
            vjn[n] = sv[jb + n * 16 + lr];
        }
        #pragma unroll
        for (int m = 0; m < 4; m++)
            #pragma unroll
            for (int n = 0; n < 4; n++)
                #pragma unroll
                for (int r = 0; r < 4; r++) {
                    float sqd = fmaxf(xs[m][r] + yr[n] - spq2 * acc[m][n][r], 0.f);
                    float rt = fsqrt(sqd);
                    float tv = rt * vjn[n];
                    a1[m][r] += tv;
                    float g = fmaf(-10.0f, rt, 1.0f);
                    a2[m][r] = fmaf(tv, g, a2[m][r]);
                }
    }
    #pragma unroll
    for (int m = 0; m < 4; m++)
        #pragma unroll
        for (int r = 0; r < 4; r++) {
            #pragma unroll
            for (int st = 1; st < 16; st <<= 1) {
                a1[m][r] += __shfl_xor(a1[m][r], st);
                a2[m][r] += __shfl_xor(a2[m][r], st);
            }
        }
    if (lr == 0) {
        #pragma unroll
        for (int m = 0; m < 4; m++)
            #pragma unroll
            for (int r = 0; r < 4; r++) {
                a1s[w][m * 16 + lk * 4 + r] = a1[m][r];
                a2s[w][m * 16 + lk * 4 + r] = a2[m][r];
            }
    }
    __syncthreads();
    if (t < 64) {
        float A1 = 0.f, A2 = 0.f;
        #pragma unroll
        for (int ww = 0; ww < 8; ww++) {
            A1 += a1s[ww][t];
            A2 += a2s[ww][t];
        }
        float u = 1.0f / (sV - 10.0f * A1 + EPS_DIV);
        float lp = u * A2;
        #pragma unroll
        for (int st = 1; st < 64; st <<= 1) lp += __shfl_xor(lp, st);
        if (t == 0) parts[b * 16 + blockIdx.x] = lp;
    }
}

__global__ void k_final(const float* __restrict__ parts, float* __restrict__ out) {
    __shared__ float sm[256];
    int t = threadIdx.x;
    float a = parts[t] + parts[t + 256];
    sm[t] = a;
    __syncthreads();
    for (int st = 128; st > 0; st >>= 1) {
        if (t < st) sm[t] += sm[t + st];
        __syncthreads();
    }
    if (t == 0) out[0] = sm[0] / (float)BATCH;
}

extern "C" void kernel_launch(void* const* d_in, const int* in_sizes, int n_in,
                              void* d_out, int out_size, void* d_ws, size_t ws_size,
                              hipStream_t stream) {
    const float* pred   = (const float*)d_in[0];
    const float* target = (const float*)d_in[1];
    float* out = (float*)d_out;

    unsigned short* xb = (unsigned short*)d_ws;                   // 8 MB bf16
    float* fs = (float*)(xb + 2 * OFFQ);
    float* rr     = fs;                                           // 2*BN
    float* v      = rr + 2 * BN;                                  // BN
    float* scpart = v + BN;                                       // 1024
    float* svpart = scpart + 1024;                                // 512
    float* parts  = svpart + 512;                                 // 512

    k_prep<<<dim3(16, 2, BATCH), 256, 0, stream>>>(pred, target, xb, rr, scpart);
    k_colsum<<<dim3(16, BATCH), 512, 0, stream>>>(xb, rr, scpart, v, svpart);
    k_loss<<<dim3(16, BATCH), 512, 0, stream>>>(xb, rr, scpart, v, svpart, parts);
    k_final<<<1, 256, 0, stream>>>(parts, out);
}